// Round 1
// baseline (392.206 us; speedup 1.0000x reference)
//
#include <hip/hip_runtime.h>
#include <cstdint>

#define NCOLS  696     // 16 + 120 + 560 subsets of size <= 3
#define NGROUP 174     // NCOLS / 4
#define RPB    4       // rows per block (one wave per row)
#define BLOCK  256

// Descriptor per output column: fields (i | j<<4 | k<<8).
// Uniform compute: L = sel(I_k, I_j); R = sel(I_j, I_i); res = sel(L, R).
//  - triple (i<j<k): exactly the reference (left = pair(j,k), right = pair(i,j))
//  - pair (a<b): encoded (i=a, j=b, k=b) -> L = I_b, R = pairres(a,b),
//      res = sel(I_b, pairres) == pairres  (fixed point, verified case-wise)
//  - single (a): encoded (a,a,a) -> res = I_a
// Emission order below generates subsets sorted by bitmask value.
struct alignas(16) Tbl { uint32_t d[NCOLS]; };

constexpr Tbl make_tbl() {
    Tbl t{};
    int p = 0;
    for (int h = 0; h < 16; ++h) {
        t.d[p++] = (uint32_t)(h | (h << 4) | (h << 8));          // {h}
        for (int j = 0; j < h; ++j) {
            t.d[p++] = (uint32_t)(j | (h << 4) | (h << 8));      // {j,h}
            for (int i = 0; i < j; ++i)
                t.d[p++] = (uint32_t)(i | (j << 4) | (h << 8));  // {i,j,h}
        }
    }
    return t;
}

__constant__ Tbl g_tbl = make_tbl();

// Exact fp32 RN ops (no FMA contraction) so tie cases (cur==nxt) match the
// NumPy fp32 reference bit-for-bit. 0.2f/0.8f match NumPy's weak-scalar cast.
__device__ __forceinline__ float2 selpair(float2 L, float2 R) {
    float cur = __fadd_rn(__fmul_rn(0.5f, L.x), __fmul_rn(0.5f, L.y));
    float nxt = __fadd_rn(__fmul_rn(0.5f, R.x), __fmul_rn(0.5f, R.y));
    float bc  = __fadd_rn(__fmul_rn(0.2f, L.x), __fmul_rn(0.8f, L.y));
    float bn  = __fadd_rn(__fmul_rn(0.2f, R.x), __fmul_rn(0.8f, R.y));
    bool choose_right = (cur == nxt) ? (bc > bn) : (cur > nxt);
    return choose_right ? R : L;
}

__device__ __forceinline__ void col_compute(const float2* __restrict__ v,
                                            uint32_t d, float& ol, float& ou) {
    float2 Ii = v[d & 15u];
    float2 Ij = v[(d >> 4) & 15u];
    float2 Ik = v[(d >> 8) & 15u];
    float2 L = selpair(Ik, Ij);
    float2 R = selpair(Ij, Ii);
    float2 res = selpair(L, R);
    ol = res.x;
    ou = res.y;
}

__global__ __launch_bounds__(BLOCK) void minint_kernel(
    const float* __restrict__ xl, const float* __restrict__ xu,
    float* __restrict__ out, int batch)
{
    __shared__ float2 vals[RPB][16];
    const int t = threadIdx.x;
    const int base = blockIdx.x * RPB;

    // Stage RPB rows of (xl,xu) into LDS as interleaved float2 intervals.
    // t in [0,64): coalesced 256B read from each input.
    if (t < RPB * 16) {
        float a = xl[base * 16 + t];
        float b = xu[base * 16 + t];
        vals[t >> 4][t & 15] = make_float2(a, b);
    }
    __syncthreads();

    const int w    = t >> 6;   // wave id == local row
    const int lane = t & 63;
    const int row  = base + w;
    const float2* v = vals[w];

    float* outl = out + (size_t)row * NCOLS;
    float* outu = out + (size_t)batch * NCOLS + (size_t)row * NCOLS;
    const uint4* tbl = (const uint4*)g_tbl.d;

    // 174 groups of 4 columns; lane g handles columns [4g, 4g+4).
    // Row byte stride = 696*4 = 174*16 -> float4 stores stay 16B-aligned.
    for (int g = lane; g < NGROUP; g += 64) {
        uint4 d4 = tbl[g];
        float4 rl, ru;
        col_compute(v, d4.x, rl.x, ru.x);
        col_compute(v, d4.y, rl.y, ru.y);
        col_compute(v, d4.z, rl.z, ru.z);
        col_compute(v, d4.w, rl.w, ru.w);
        *(float4*)(outl + 4 * g) = rl;   // coalesced: lanes -> consecutive float4
        *(float4*)(outu + 4 * g) = ru;
    }
}

extern "C" void kernel_launch(void* const* d_in, const int* in_sizes, int n_in,
                              void* d_out, int out_size, void* d_ws, size_t ws_size,
                              hipStream_t stream) {
    const float* xl = (const float*)d_in[0];
    const float* xu = (const float*)d_in[1];
    float* out = (float*)d_out;
    const int batch = in_sizes[0] / 16;          // 65536
    const int grid  = batch / RPB;               // 16384 blocks x 4 waves
    minint_kernel<<<grid, BLOCK, 0, stream>>>(xl, xu, out, batch);
}

// Round 4
// 374.570 us; speedup vs baseline: 1.0471x; 1.0471x over previous
//
#include <hip/hip_runtime.h>
#include <cstdint>

#define NCOLS  696     // 16 + 120 + 560 subsets of size <= 3, bitmask order
#define NGROUP 174     // NCOLS / 4
#define NREC   136     // 16 singles + 120 pairs
#define RPB    4       // rows per block (one wave per row)
#define BLOCK  256

typedef float v4f __attribute__((ext_vector_type(4)));  // clang vector: ok for nontemporal builtin

// Record id: single a -> a ; pair (a<b) -> 16 + b*(b-1)/2 + a.
constexpr int pr(int a, int b) { return 16 + b * (b - 1) / 2 + a; }

// Per-record source operands (lo | hi<<8): rec[r] = selpair(v[hi], v[lo]).
//  single a: (a,a) -> selpair(I_a, I_a) = I_a (tie, beta tie, choose left).
//  pair (a<b): selpair(L=I_b, R=I_a) = reference pairres(a,b).
struct alignas(8) RecSrc { uint16_t d[NREC]; };
constexpr RecSrc make_recs() {
    RecSrc t{};
    for (int a = 0; a < 16; ++a) t.d[a] = (uint16_t)(a | (a << 8));
    int p = 16;
    for (int b = 1; b < 16; ++b)
        for (int a = 0; a < b; ++a)
            t.d[p++] = (uint16_t)(a | (b << 8));
    return t;
}

// Per-column descriptor (Lrec | Rrec<<8): out = selpair(rec[Lrec], rec[Rrec]).
//  single {h}:   L = R = h            (selpair(X,X) == X)
//  pair {j,h}:   L = R = pr(j,h)
//  triple {i,j,h}: L = pr(j,h) (= combo[1:]), R = pr(i,j) (= combo[:-1])
// Emission order generates subsets sorted by bitmask value.
struct alignas(8) ColTbl { uint16_t d[NCOLS]; };
constexpr ColTbl make_cols() {
    ColTbl t{};
    int p = 0;
    for (int h = 0; h < 16; ++h) {
        t.d[p++] = (uint16_t)(h | (h << 8));
        for (int j = 0; j < h; ++j) {
            int pjh = pr(j, h);
            t.d[p++] = (uint16_t)(pjh | (pjh << 8));
            for (int i = 0; i < j; ++i)
                t.d[p++] = (uint16_t)(pr(j, h) | (pr(i, j) << 8));
        }
    }
    return t;
}

__constant__ RecSrc g_recs = make_recs();
__constant__ ColTbl g_cols = make_cols();

// Tie-exact select. cur comparison uses the sum proxy: RN(0.5l+0.5u) =
// 0.5*RN(l+u) exactly (power-of-two scaling), so ==/> are preserved
// bit-for-bit vs the NumPy fp32 reference. Beta path kept in RN form.
__device__ __forceinline__ float2 selpair(float2 L, float2 R) {
    float curL = __fadd_rn(L.x, L.y);
    float curR = __fadd_rn(R.x, R.y);
    float bL = __fadd_rn(__fmul_rn(0.2f, L.x), __fmul_rn(0.8f, L.y));
    float bR = __fadd_rn(__fmul_rn(0.2f, R.x), __fmul_rn(0.8f, R.y));
    bool choose_right = (curL == curR) ? (bL > bR) : (curL > curR);
    return choose_right ? R : L;
}

__device__ __forceinline__ float2 col_compute(const float2* __restrict__ rec,
                                              uint32_t d) {
    float2 L = rec[d & 255u];
    float2 R = rec[(d >> 8) & 255u];
    return selpair(L, R);
}

__global__ __launch_bounds__(BLOCK) void minint_kernel(
    const float* __restrict__ xl, const float* __restrict__ xu,
    float* __restrict__ out, int batch)
{
    __shared__ float2 vals[RPB][16];
    __shared__ float2 recs[RPB][NREC];
    const int t = threadIdx.x;
    const int base = blockIdx.x * RPB;

    // Stage RPB rows of (xl,xu) into LDS as interleaved float2 intervals.
    if (t < RPB * 16) {
        float a = xl[base * 16 + t];
        float b = xu[base * 16 + t];
        vals[t >> 4][t & 15] = make_float2(a, b);
    }
    __syncthreads();

    const int w    = t >> 6;   // wave id == local row
    const int lane = t & 63;
    const float2* v = vals[w];

    // Precompute the 136 single/pair records for this wave's row.
    for (int r = lane; r < NREC; r += 64) {
        uint32_t s = g_recs.d[r];
        float2 lo = v[s & 15u];
        float2 hi = v[(s >> 8) & 15u];
        recs[w][r] = selpair(hi, lo);
    }
    __syncthreads();

    const int row = base + w;
    const float2* rec = recs[w];
    float* outl = out + (size_t)row * NCOLS;
    float* outu = out + (size_t)batch * NCOLS + (size_t)row * NCOLS;
    const ushort4* cols = (const ushort4*)g_cols.d;

    // 174 groups of 4 columns; lane g handles columns [4g, 4g+4).
    // Row byte stride = 696*4 = 174*16 -> float4 stores stay 16B-aligned.
    for (int g = lane; g < NGROUP; g += 64) {
        ushort4 d4 = cols[g];
        float2 c0 = col_compute(rec, d4.x);
        float2 c1 = col_compute(rec, d4.y);
        float2 c2 = col_compute(rec, d4.z);
        float2 c3 = col_compute(rec, d4.w);
        v4f rl = { c0.x, c1.x, c2.x, c3.x };
        v4f ru = { c0.y, c1.y, c2.y, c3.y };
        __builtin_nontemporal_store(rl, (v4f*)(outl + 4 * g));
        __builtin_nontemporal_store(ru, (v4f*)(outu + 4 * g));
    }
}

extern "C" void kernel_launch(void* const* d_in, const int* in_sizes, int n_in,
                              void* d_out, int out_size, void* d_ws, size_t ws_size,
                              hipStream_t stream) {
    const float* xl = (const float*)d_in[0];
    const float* xu = (const float*)d_in[1];
    float* out = (float*)d_out;
    const int batch = in_sizes[0] / 16;          // 65536
    const int grid  = batch / RPB;               // 16384 blocks x 4 waves
    minint_kernel<<<grid, BLOCK, 0, stream>>>(xl, xu, out, batch);
}